// Round 1
// baseline (3261.533 us; speedup 1.0000x reference)
//
#include <hip/hip_runtime.h>
#include <hip/hip_bf16.h>
#include <cstdint>
#include <cstddef>

typedef __bf16 bf16;
typedef __bf16 bf16x2 __attribute__((ext_vector_type(2)));
typedef __bf16 bf16x4 __attribute__((ext_vector_type(4)));
typedef __bf16 bf16x8 __attribute__((ext_vector_type(8)));
typedef float f32x4 __attribute__((ext_vector_type(4)));

static_assert(sizeof(bf16x8) == 16, "bf16x8 must be 16B");

#define NE 16384   // E
#define ND 1024    // D
#define NA 512     // A
#define NM 2048    // M
#define NH 3
#define NRES 3

// ---------------------------------------------------------------------------
// async global->LDS, 16B per lane (wave-uniform LDS base + lane*16 implicit)
__device__ __forceinline__ void async_ld16(const bf16* g, bf16* l) {
  __builtin_amdgcn_global_load_lds(
      (__attribute__((address_space(1))) void*)(void*)g,
      (__attribute__((address_space(3))) void*)(void*)l,
      16, 0, 0);
}

// ---------------------------------------------------------------------------
// Generic bf16 GEMM: C[M,N] = A[M,K] @ B^T[N,K]  (both row-major bf16),
// fp32 accum, templated epilogue.
// MODE 0: C_bf16 = acc + bias[n]
// MODE 1: C_bf16 = addb[m,n] + relu(acc + bias[n])        (residual, in-place)
// MODE 2: C_bf16[m, coloff+n] = acc + bias[n] + addb[m,n] (head_out -> cat)
// MODE 3: C_f32[m,n] += acc                               (final += Q-K)
template <int MODE>
__global__ __launch_bounds__(256) void gemm_kernel(
    const bf16* __restrict__ A, const bf16* __restrict__ B,
    const float* __restrict__ bias, void* __restrict__ Cv,
    const bf16* __restrict__ addb, int K, int ldc, int coloff, int addld) {
  // LDS tiles: 128 rows x 64 cols, stored in 8-elem (16B) chunks with
  // chunk-slot XOR swizzle: slot s at row r holds logical chunk c = s ^ (r&7).
  __shared__ bf16 lA[128 * 64];
  __shared__ bf16 lB[128 * 64];

  const int tid = threadIdx.x;
  const int wv = tid >> 6, ln = tid & 63;
  const int wm = wv & 1, wn = wv >> 1;      // 2x2 waves, each 64x64
  const int m0 = blockIdx.y * 128, n0 = blockIdx.x * 128;

  f32x4 acc[4][4] = {};

  const int rb = wv * 32 + (ln >> 3);       // + it*8
  const int slot = ln & 7;

  for (int k0 = 0; k0 < K; k0 += 64) {
#pragma unroll
    for (int it = 0; it < 4; ++it) {
      const int r = rb + it * 8;
      const int c = slot ^ (r & 7);         // logical chunk this lane fetches
      async_ld16(A + (size_t)(m0 + r) * K + k0 + c * 8,
                 &lA[(wv * 32 + it * 8) * 64]);
      async_ld16(B + (size_t)(n0 + r) * K + k0 + c * 8,
                 &lB[(wv * 32 + it * 8) * 64]);
    }
    __syncthreads();
#pragma unroll
    for (int kk = 0; kk < 2; ++kk) {
      bf16x8 fa[4], fb[4];
      const int cl = kk * 4 + (ln >> 4);    // logical chunk for this quad
#pragma unroll
      for (int i = 0; i < 4; ++i) {
        const int ra = wm * 64 + i * 16 + (ln & 15);
        fa[i] = *(const bf16x8*)&lA[ra * 64 + ((cl ^ (ra & 7)) * 8)];
        const int rbn = wn * 64 + i * 16 + (ln & 15);
        fb[i] = *(const bf16x8*)&lB[rbn * 64 + ((cl ^ (rbn & 7)) * 8)];
      }
#pragma unroll
      for (int i = 0; i < 4; ++i)
#pragma unroll
        for (int j = 0; j < 4; ++j)
          acc[i][j] = __builtin_amdgcn_mfma_f32_16x16x32_bf16(
              fa[i], fb[j], acc[i][j], 0, 0, 0);
    }
    __syncthreads();
  }

  // epilogue: C/D layout row=(ln>>4)*4+r, col=ln&15 within each 16x16 tile
  const int q4 = (ln >> 4) * 4, c16 = ln & 15;
#pragma unroll
  for (int i = 0; i < 4; ++i) {
#pragma unroll
    for (int j = 0; j < 4; ++j) {
#pragma unroll
      for (int r = 0; r < 4; ++r) {
        const int mi = m0 + wm * 64 + i * 16 + q4 + r;
        const int ni = n0 + wn * 64 + j * 16 + c16;
        float v = acc[i][j][r];
        if constexpr (MODE != 3) v += bias[ni];
        if constexpr (MODE == 0) {
          ((bf16*)Cv)[(size_t)mi * ldc + ni] = (bf16)v;
        } else if constexpr (MODE == 1) {
          float prev = (float)addb[(size_t)mi * addld + ni];
          ((bf16*)Cv)[(size_t)mi * ldc + ni] = (bf16)(prev + fmaxf(v, 0.f));
        } else if constexpr (MODE == 2) {
          v += (float)addb[(size_t)mi * addld + ni];
          ((bf16*)Cv)[(size_t)mi * ldc + coloff + ni] = (bf16)v;
        } else {
          float* C = (float*)Cv;
          const size_t idx = (size_t)mi * ldc + ni;
          C[idx] = C[idx] + v;
        }
      }
    }
  }
}

template <int MODE>
static void launch_gemm(hipStream_t s, const bf16* A, const bf16* B,
                        const float* bias, void* C, const bf16* addb, int M,
                        int N, int K, int ldc, int coloff, int addld) {
  dim3 grid(N / 128, M / 128);
  gemm_kernel<MODE><<<grid, 256, 0, s>>>(A, B, bias, C, addb, K, ldc, coloff,
                                         addld);
}

// ---------------------------------------------------------------------------
// fp32 [K,N] -> bf16 [N,K] transpose-convert, 32x32 tiles, batched over z
__global__ void transpose_cvt(const float* __restrict__ src,
                              bf16* __restrict__ dst, int K, int N) {
  __shared__ float t[32][33];
  const size_t zo = (size_t)blockIdx.z * K * N;
  src += zo;
  dst += zo;
  const int n = blockIdx.x * 32 + threadIdx.x;
  const int kb = blockIdx.y * 32;
#pragma unroll
  for (int i = 0; i < 4; ++i) {
    const int k = kb + threadIdx.y + i * 8;
    t[threadIdx.y + i * 8][threadIdx.x] = src[(size_t)k * N + n];
  }
  __syncthreads();
#pragma unroll
  for (int i = 0; i < 4; ++i) {
    const int nn = blockIdx.x * 32 + threadIdx.y + i * 8;
    dst[(size_t)nn * K + kb + threadIdx.x] =
        (bf16)t[threadIdx.x][threadIdx.y + i * 8];
  }
}

// ---------------------------------------------------------------------------
// Q = normalize(h)[src], K = rep[dst]; emit bf16 Q,K and fp32 (Q-K) -> d_out
__global__ __launch_bounds__(256) void gather_kernel(
    const float* __restrict__ h, const float* __restrict__ rep,
    const int* __restrict__ src, const int* __restrict__ dst,
    bf16* __restrict__ Qb, bf16* __restrict__ Kb, float* __restrict__ qk) {
  __shared__ float sm[4];
  const int e = blockIdx.x, tid = threadIdx.x;
  const int sr = src[e], dr = dst[e];
  const float4 hv = ((const float4*)(h + (size_t)sr * ND))[tid];
  float ss = hv.x * hv.x + hv.y * hv.y + hv.z * hv.z + hv.w * hv.w;
#pragma unroll
  for (int o = 32; o > 0; o >>= 1) ss += __shfl_down(ss, o, 64);
  if ((tid & 63) == 0) sm[tid >> 6] = ss;
  __syncthreads();
  const float tot = sm[0] + sm[1] + sm[2] + sm[3];
  const float inv = 1.f / fmaxf(sqrtf(tot), 1e-12f);
  const float4 rv = ((const float4*)(rep + (size_t)dr * ND))[tid];
  const float q0 = hv.x * inv, q1 = hv.y * inv, q2 = hv.z * inv,
              q3 = hv.w * inv;
  const size_t base = (size_t)e * ND + tid * 4;
  bf16x4 qv;
  qv[0] = (bf16)q0; qv[1] = (bf16)q1; qv[2] = (bf16)q2; qv[3] = (bf16)q3;
  *(bf16x4*)(Qb + base) = qv;
  bf16x4 kv;
  kv[0] = (bf16)rv.x; kv[1] = (bf16)rv.y; kv[2] = (bf16)rv.z;
  kv[3] = (bf16)rv.w;
  *(bf16x4*)(Kb + base) = kv;
  *(float4*)(qk + base) =
      make_float4(q0 - rv.x, q1 - rv.y, q2 - rv.z, q3 - rv.w);
}

// ---------------------------------------------------------------------------
// attn = softmax(Qp*Kp/sqrt(A), axis=-1) * Vp   (per row of 512)
__global__ __launch_bounds__(256) void softmax_kernel(
    const bf16* __restrict__ Qp, const bf16* __restrict__ Kp,
    const bf16* __restrict__ Vp, bf16* __restrict__ attn) {
  __shared__ float sm[4];
  const int tid = threadIdx.x;
  const size_t base = (size_t)blockIdx.x * NA + 2 * tid;
  const bf16x2 q = *(const bf16x2*)(Qp + base);
  const bf16x2 k = *(const bf16x2*)(Kp + base);
  const bf16x2 v = *(const bf16x2*)(Vp + base);
  const float sc = 0.044194173824159216f;  // 1/sqrt(512)
  const float s0 = (float)q[0] * (float)k[0] * sc;
  const float s1 = (float)q[1] * (float)k[1] * sc;
  float mx = fmaxf(s0, s1);
#pragma unroll
  for (int o = 32; o > 0; o >>= 1) mx = fmaxf(mx, __shfl_down(mx, o, 64));
  if ((tid & 63) == 0) sm[tid >> 6] = mx;
  __syncthreads();
  mx = fmaxf(fmaxf(sm[0], sm[1]), fmaxf(sm[2], sm[3]));
  __syncthreads();
  const float p0 = expf(s0 - mx), p1 = expf(s1 - mx);
  float ssum = p0 + p1;
#pragma unroll
  for (int o = 32; o > 0; o >>= 1) ssum += __shfl_down(ssum, o, 64);
  if ((tid & 63) == 0) sm[tid >> 6] = ssum;
  __syncthreads();
  const float inv = 1.f / (sm[0] + sm[1] + sm[2] + sm[3]);
  bf16x2 r;
  r[0] = (bf16)(p0 * inv * (float)v[0]);
  r[1] = (bf16)(p1 * inv * (float)v[1]);
  *(bf16x2*)(attn + base) = r;
}

// ---------------------------------------------------------------------------
// y = LN(x) * g + b over rows of 2048
__global__ __launch_bounds__(256) void ln_kernel(const bf16* __restrict__ x,
                                                 bf16* __restrict__ y,
                                                 const float* __restrict__ g,
                                                 const float* __restrict__ b) {
  __shared__ float sm[8];
  const int tid = threadIdx.x;
  const size_t base = (size_t)blockIdx.x * NM + tid * 8;
  const bf16x8 xv = *(const bf16x8*)(x + base);
  float xf[8], s = 0.f, ss = 0.f;
#pragma unroll
  for (int i = 0; i < 8; ++i) {
    xf[i] = (float)xv[i];
    s += xf[i];
    ss += xf[i] * xf[i];
  }
#pragma unroll
  for (int o = 32; o > 0; o >>= 1) {
    s += __shfl_down(s, o, 64);
    ss += __shfl_down(ss, o, 64);
  }
  if ((tid & 63) == 0) {
    sm[tid >> 6] = s;
    sm[4 + (tid >> 6)] = ss;
  }
  __syncthreads();
  s = sm[0] + sm[1] + sm[2] + sm[3];
  ss = sm[4] + sm[5] + sm[6] + sm[7];
  const float mu = s * (1.f / NM);
  const float var = ss * (1.f / NM) - mu * mu;
  const float rstd = rsqrtf(fmaxf(var, 0.f) + 1e-5f);
  const int c0 = tid * 8;
  bf16x8 yv;
#pragma unroll
  for (int i = 0; i < 8; ++i)
    yv[i] = (bf16)((xf[i] - mu) * rstd * g[c0 + i] + b[c0 + i]);
  *(bf16x8*)(y + base) = yv;
}

// ---------------------------------------------------------------------------
extern "C" void kernel_launch(void* const* d_in, const int* in_sizes, int n_in,
                              void* d_out, int out_size, void* d_ws,
                              size_t ws_size, hipStream_t stream) {
  const float* h    = (const float*)d_in[0];
  const float* rep  = (const float*)d_in[1];
  const int* src    = (const int*)d_in[2];
  const int* dst    = (const int*)d_in[3];
  const float* Wq   = (const float*)d_in[4];
  const float* bq   = (const float*)d_in[5];
  const float* Wk   = (const float*)d_in[6];
  const float* bk   = (const float*)d_in[7];
  const float* Wv   = (const float*)d_in[8];
  const float* bv   = (const float*)d_in[9];
  const float* W0   = (const float*)d_in[10];
  const float* b0   = (const float*)d_in[11];
  const float* Wr   = (const float*)d_in[12];
  const float* br   = (const float*)d_in[13];
  const float* g_ln = (const float*)d_in[14];
  const float* b_ln = (const float*)d_in[15];
  const float* Wms  = (const float*)d_in[16];
  const float* bms  = (const float*)d_in[17];
  const float* Wuas = (const float*)d_in[18];
  float* out = (float*)d_out;

  bf16* ws = (bf16*)d_ws;
  size_t off = 0;
  auto alloc = [&](size_t n) {
    bf16* p = ws + off;
    off += n;
    return p;
  };
  bf16* WqT   = alloc((size_t)NH * NA * ND);       // [h][512][1024]
  bf16* WkT   = alloc((size_t)NH * NA * ND);
  bf16* WvT   = alloc((size_t)NH * NA * ND);
  bf16* W0T   = alloc((size_t)NH * NM * NA);       // [h][2048][512]
  bf16* WrT   = alloc((size_t)NH * NRES * NM * NM);// [h*3+j][2048][2048]
  bf16* WmsT  = alloc((size_t)NH * NA * NM);       // [h][512][2048]
  bf16* WuasT = alloc((size_t)ND * NH * NA);       // [1024][1536]
  bf16* Qb    = alloc((size_t)NE * ND);
  bf16* Kb    = alloc((size_t)NE * ND);
  bf16* Qp    = alloc((size_t)NE * NA);
  bf16* Kp    = alloc((size_t)NE * NA);
  bf16* Vp    = alloc((size_t)NE * NA);
  bf16* attn  = alloc((size_t)NE * NA);
  bf16* mbuf  = alloc((size_t)NE * NM);
  bf16* xnb   = alloc((size_t)NE * NM);
  bf16* cat   = alloc((size_t)NE * NH * NA);
  if (ws_size < off * sizeof(bf16)) return;  // workspace too small: bail

  const dim3 tb(32, 8);
  transpose_cvt<<<dim3(NA / 32, ND / 32, NH), tb, 0, stream>>>(Wq, WqT, ND, NA);
  transpose_cvt<<<dim3(NA / 32, ND / 32, NH), tb, 0, stream>>>(Wk, WkT, ND, NA);
  transpose_cvt<<<dim3(NA / 32, ND / 32, NH), tb, 0, stream>>>(Wv, WvT, ND, NA);
  transpose_cvt<<<dim3(NM / 32, NA / 32, NH), tb, 0, stream>>>(W0, W0T, NA, NM);
  transpose_cvt<<<dim3(NM / 32, NM / 32, NH * NRES), tb, 0, stream>>>(Wr, WrT,
                                                                      NM, NM);
  transpose_cvt<<<dim3(NA / 32, NM / 32, NH), tb, 0, stream>>>(Wms, WmsT, NM,
                                                               NA);
  transpose_cvt<<<dim3(ND / 32, (NH * NA) / 32, 1), tb, 0, stream>>>(
      Wuas, WuasT, NH * NA, ND);

  gather_kernel<<<NE, 256, 0, stream>>>(h, rep, src, dst, Qb, Kb, out);

  for (int hh = 0; hh < NH; ++hh) {
    launch_gemm<0>(stream, Qb, WqT + (size_t)hh * NA * ND, bq + hh * NA, Qp,
                   nullptr, NE, NA, ND, NA, 0, 0);
    launch_gemm<0>(stream, Kb, WkT + (size_t)hh * NA * ND, bk + hh * NA, Kp,
                   nullptr, NE, NA, ND, NA, 0, 0);
    launch_gemm<0>(stream, Kb, WvT + (size_t)hh * NA * ND, bv + hh * NA, Vp,
                   nullptr, NE, NA, ND, NA, 0, 0);
    softmax_kernel<<<NE, 256, 0, stream>>>(Qp, Kp, Vp, attn);
    launch_gemm<0>(stream, attn, W0T + (size_t)hh * NM * NA, b0 + hh * NM,
                   mbuf, nullptr, NE, NM, NA, NM, 0, 0);
    for (int j = 0; j < NRES; ++j) {
      const int hj = hh * NRES + j;
      ln_kernel<<<NE, 256, 0, stream>>>(mbuf, xnb, g_ln + (size_t)hj * NM,
                                        b_ln + (size_t)hj * NM);
      launch_gemm<1>(stream, xnb, WrT + (size_t)hj * NM * NM, br + hj * NM,
                     mbuf, mbuf, NE, NM, NM, NM, 0, NM);
    }
    launch_gemm<2>(stream, mbuf, WmsT + (size_t)hh * NA * NM, bms + hh * NA,
                   cat, attn, NE, NA, NM, NH * NA, hh * NA, NA);
  }
  launch_gemm<3>(stream, cat, WuasT, nullptr, out, nullptr, NE, ND, NH * NA,
                 ND, 0, 0);
}

// Round 2
// 3048.992 us; speedup vs baseline: 1.0697x; 1.0697x over previous
//
#include <hip/hip_runtime.h>
#include <hip/hip_bf16.h>
#include <cstdint>
#include <cstddef>

typedef __bf16 bf16;
typedef __bf16 bf16x2 __attribute__((ext_vector_type(2)));
typedef __bf16 bf16x4 __attribute__((ext_vector_type(4)));
typedef __bf16 bf16x8 __attribute__((ext_vector_type(8)));
typedef float f32x16 __attribute__((ext_vector_type(16)));

static_assert(sizeof(bf16x8) == 16, "bf16x8 must be 16B");

#define NE 16384   // E
#define ND 1024    // D
#define NA 512     // A
#define NM 2048    // M
#define NH 3
#define NRES 3

// ---------------------------------------------------------------------------
// async global->LDS, 16B per lane (wave-uniform LDS base + lane*16 implicit)
__device__ __forceinline__ void async_ld16(const bf16* g, bf16* l) {
  __builtin_amdgcn_global_load_lds(
      (__attribute__((address_space(1))) void*)(void*)g,
      (__attribute__((address_space(3))) void*)(void*)l,
      16, 0, 0);
}

// ---------------------------------------------------------------------------
// Generic bf16 GEMM: C[M,N] = A[M,K] @ B^T[N,K]  (both row-major bf16),
// fp32 accum via v_mfma_f32_32x32x16_bf16, templated epilogue.
// MODE 0: C_bf16 = acc + bias[n]
// MODE 1: C_bf16 = addb[m,n] + relu(acc + bias[n])        (residual, in-place)
// MODE 2: C_bf16[m, coloff+n] = acc + bias[n] + addb[m,n] (head_out -> cat)
// MODE 3: C_f32[m,n] += acc                               (final += Q-K)
template <int MODE>
__global__ __launch_bounds__(256) void gemm_kernel(
    const bf16* __restrict__ A, const bf16* __restrict__ B,
    const float* __restrict__ bias, void* __restrict__ Cv,
    const bf16* __restrict__ addb, int K, int ldc, int coloff, int addld) {
  // LDS tiles: 128 rows x 64 cols, stored in 8-elem (16B) chunks with
  // chunk-slot XOR swizzle: slot s at row r holds logical chunk c = s ^ (r&7).
  __shared__ bf16 lA[128 * 64];
  __shared__ bf16 lB[128 * 64];

  const int tid = threadIdx.x;
  const int wv = tid >> 6, ln = tid & 63;
  const int wm = wv & 1, wn = wv >> 1;      // 2x2 waves, each 64x64
  const int m0 = blockIdx.y * 128, n0 = blockIdx.x * 128;

  f32x16 acc[2][2] = {};

  const int rb = wv * 32 + (ln >> 3);       // + it*8
  const int slot = ln & 7;

  for (int k0 = 0; k0 < K; k0 += 64) {
#pragma unroll
    for (int it = 0; it < 4; ++it) {
      const int r = rb + it * 8;
      const int c = slot ^ (r & 7);         // logical chunk this lane fetches
      async_ld16(A + (size_t)(m0 + r) * K + k0 + c * 8,
                 &lA[(wv * 32 + it * 8) * 64]);
      async_ld16(B + (size_t)(n0 + r) * K + k0 + c * 8,
                 &lB[(wv * 32 + it * 8) * 64]);
    }
    __syncthreads();
#pragma unroll
    for (int kk = 0; kk < 4; ++kk) {
      bf16x8 fa[2], fb[2];
      const int cl = kk * 2 + (ln >> 5);    // logical chunk for this half-wave
#pragma unroll
      for (int i = 0; i < 2; ++i) {
        const int ra = wm * 64 + i * 32 + (ln & 31);
        fa[i] = *(const bf16x8*)&lA[ra * 64 + ((cl ^ (ra & 7)) * 8)];
        const int rbn = wn * 64 + i * 32 + (ln & 31);
        fb[i] = *(const bf16x8*)&lB[rbn * 64 + ((cl ^ (rbn & 7)) * 8)];
      }
#pragma unroll
      for (int i = 0; i < 2; ++i)
#pragma unroll
        for (int j = 0; j < 2; ++j)
          acc[i][j] = __builtin_amdgcn_mfma_f32_32x32x16_bf16(
              fa[i], fb[j], acc[i][j], 0, 0, 0);
    }
    __syncthreads();
  }

  // epilogue: 32x32 C/D layout col=ln&31, row=(r&3)+8*(r>>2)+4*(ln>>5)
  const int cR = ln & 31, half4 = (ln >> 5) * 4;
#pragma unroll
  for (int i = 0; i < 2; ++i) {
#pragma unroll
    for (int j = 0; j < 2; ++j) {
#pragma unroll
      for (int r = 0; r < 16; ++r) {
        const int mi = m0 + wm * 64 + i * 32 + (r & 3) + 8 * (r >> 2) + half4;
        const int ni = n0 + wn * 64 + j * 32 + cR;
        float v = acc[i][j][r];
        if constexpr (MODE != 3) v += bias[ni];
        if constexpr (MODE == 0) {
          ((bf16*)Cv)[(size_t)mi * ldc + ni] = (bf16)v;
        } else if constexpr (MODE == 1) {
          float prev = (float)addb[(size_t)mi * addld + ni];
          ((bf16*)Cv)[(size_t)mi * ldc + ni] = (bf16)(prev + fmaxf(v, 0.f));
        } else if constexpr (MODE == 2) {
          v += (float)addb[(size_t)mi * addld + ni];
          ((bf16*)Cv)[(size_t)mi * ldc + coloff + ni] = (bf16)v;
        } else {
          float* C = (float*)Cv;
          const size_t idx = (size_t)mi * ldc + ni;
          C[idx] = C[idx] + v;
        }
      }
    }
  }
}

template <int MODE>
static void launch_gemm(hipStream_t s, const bf16* A, const bf16* B,
                        const float* bias, void* C, const bf16* addb, int M,
                        int N, int K, int ldc, int coloff, int addld) {
  dim3 grid(N / 128, M / 128);
  gemm_kernel<MODE><<<grid, 256, 0, s>>>(A, B, bias, C, addb, K, ldc, coloff,
                                         addld);
}

// ---------------------------------------------------------------------------
// fp32 [K,N] -> bf16 [N,K] transpose-convert, 32x32 tiles, batched over z
__global__ void transpose_cvt(const float* __restrict__ src,
                              bf16* __restrict__ dst, int K, int N) {
  __shared__ float t[32][33];
  const size_t zo = (size_t)blockIdx.z * K * N;
  src += zo;
  dst += zo;
  const int n = blockIdx.x * 32 + threadIdx.x;
  const int kb = blockIdx.y * 32;
#pragma unroll
  for (int i = 0; i < 4; ++i) {
    const int k = kb + threadIdx.y + i * 8;
    t[threadIdx.y + i * 8][threadIdx.x] = src[(size_t)k * N + n];
  }
  __syncthreads();
#pragma unroll
  for (int i = 0; i < 4; ++i) {
    const int nn = blockIdx.x * 32 + threadIdx.y + i * 8;
    dst[(size_t)nn * K + kb + threadIdx.x] =
        (bf16)t[threadIdx.x][threadIdx.y + i * 8];
  }
}

// ---------------------------------------------------------------------------
// Q = normalize(h)[src], K = rep[dst]; emit bf16 Q,K and fp32 (Q-K) -> d_out
__global__ __launch_bounds__(256) void gather_kernel(
    const float* __restrict__ h, const float* __restrict__ rep,
    const int* __restrict__ src, const int* __restrict__ dst,
    bf16* __restrict__ Qb, bf16* __restrict__ Kb, float* __restrict__ qk) {
  __shared__ float sm[4];
  const int e = blockIdx.x, tid = threadIdx.x;
  const int sr = src[e], dr = dst[e];
  const float4 hv = ((const float4*)(h + (size_t)sr * ND))[tid];
  float ss = hv.x * hv.x + hv.y * hv.y + hv.z * hv.z + hv.w * hv.w;
#pragma unroll
  for (int o = 32; o > 0; o >>= 1) ss += __shfl_down(ss, o, 64);
  if ((tid & 63) == 0) sm[tid >> 6] = ss;
  __syncthreads();
  const float tot = sm[0] + sm[1] + sm[2] + sm[3];
  const float inv = 1.f / fmaxf(sqrtf(tot), 1e-12f);
  const float4 rv = ((const float4*)(rep + (size_t)dr * ND))[tid];
  const float q0 = hv.x * inv, q1 = hv.y * inv, q2 = hv.z * inv,
              q3 = hv.w * inv;
  const size_t base = (size_t)e * ND + tid * 4;
  bf16x4 qv;
  qv[0] = (bf16)q0; qv[1] = (bf16)q1; qv[2] = (bf16)q2; qv[3] = (bf16)q3;
  *(bf16x4*)(Qb + base) = qv;
  bf16x4 kv;
  kv[0] = (bf16)rv.x; kv[1] = (bf16)rv.y; kv[2] = (bf16)rv.z;
  kv[3] = (bf16)rv.w;
  *(bf16x4*)(Kb + base) = kv;
  *(float4*)(qk + base) =
      make_float4(q0 - rv.x, q1 - rv.y, q2 - rv.z, q3 - rv.w);
}

// ---------------------------------------------------------------------------
// attn = softmax(Qp*Kp/sqrt(A), axis=-1) * Vp   (per row of 512)
// Qp/Kp/Vp are [E][H*A]; attn out is [h][E][A]. grid = (E, H).
__global__ __launch_bounds__(256) void softmax_kernel(
    const bf16* __restrict__ Qp, const bf16* __restrict__ Kp,
    const bf16* __restrict__ Vp, bf16* __restrict__ attn) {
  __shared__ float sm[4];
  const int tid = threadIdx.x;
  const int e = blockIdx.x, hh = blockIdx.y;
  const size_t base = (size_t)e * (NH * NA) + (size_t)hh * NA + 2 * tid;
  const bf16x2 q = *(const bf16x2*)(Qp + base);
  const bf16x2 k = *(const bf16x2*)(Kp + base);
  const bf16x2 v = *(const bf16x2*)(Vp + base);
  const float sc = 0.044194173824159216f;  // 1/sqrt(512)
  const float s0 = (float)q[0] * (float)k[0] * sc;
  const float s1 = (float)q[1] * (float)k[1] * sc;
  float mx = fmaxf(s0, s1);
#pragma unroll
  for (int o = 32; o > 0; o >>= 1) mx = fmaxf(mx, __shfl_down(mx, o, 64));
  if ((tid & 63) == 0) sm[tid >> 6] = mx;
  __syncthreads();
  mx = fmaxf(fmaxf(sm[0], sm[1]), fmaxf(sm[2], sm[3]));
  __syncthreads();
  const float p0 = expf(s0 - mx), p1 = expf(s1 - mx);
  float ssum = p0 + p1;
#pragma unroll
  for (int o = 32; o > 0; o >>= 1) ssum += __shfl_down(ssum, o, 64);
  if ((tid & 63) == 0) sm[tid >> 6] = ssum;
  __syncthreads();
  const float inv = 1.f / (sm[0] + sm[1] + sm[2] + sm[3]);
  bf16x2 r;
  r[0] = (bf16)(p0 * inv * (float)v[0]);
  r[1] = (bf16)(p1 * inv * (float)v[1]);
  const size_t obase = (size_t)hh * NE * NA + (size_t)e * NA + 2 * tid;
  *(bf16x2*)(attn + obase) = r;
}

// ---------------------------------------------------------------------------
// y = LN(x) * g + b over rows of 2048
__global__ __launch_bounds__(256) void ln_kernel(const bf16* __restrict__ x,
                                                 bf16* __restrict__ y,
                                                 const float* __restrict__ g,
                                                 const float* __restrict__ b) {
  __shared__ float sm[8];
  const int tid = threadIdx.x;
  const size_t base = (size_t)blockIdx.x * NM + tid * 8;
  const bf16x8 xv = *(const bf16x8*)(x + base);
  float xf[8], s = 0.f, ss = 0.f;
#pragma unroll
  for (int i = 0; i < 8; ++i) {
    xf[i] = (float)xv[i];
    s += xf[i];
    ss += xf[i] * xf[i];
  }
#pragma unroll
  for (int o = 32; o > 0; o >>= 1) {
    s += __shfl_down(s, o, 64);
    ss += __shfl_down(ss, o, 64);
  }
  if ((tid & 63) == 0) {
    sm[tid >> 6] = s;
    sm[4 + (tid >> 6)] = ss;
  }
  __syncthreads();
  s = sm[0] + sm[1] + sm[2] + sm[3];
  ss = sm[4] + sm[5] + sm[6] + sm[7];
  const float mu = s * (1.f / NM);
  const float var = ss * (1.f / NM) - mu * mu;
  const float rstd = rsqrtf(fmaxf(var, 0.f) + 1e-5f);
  const int c0 = tid * 8;
  bf16x8 yv;
#pragma unroll
  for (int i = 0; i < 8; ++i)
    yv[i] = (bf16)((xf[i] - mu) * rstd * g[c0 + i] + b[c0 + i]);
  *(bf16x8*)(y + base) = yv;
}

// ---------------------------------------------------------------------------
extern "C" void kernel_launch(void* const* d_in, const int* in_sizes, int n_in,
                              void* d_out, int out_size, void* d_ws,
                              size_t ws_size, hipStream_t stream) {
  const float* h    = (const float*)d_in[0];
  const float* rep  = (const float*)d_in[1];
  const int* src    = (const int*)d_in[2];
  const int* dst    = (const int*)d_in[3];
  const float* Wq   = (const float*)d_in[4];
  const float* bq   = (const float*)d_in[5];
  const float* Wk   = (const float*)d_in[6];
  const float* bk   = (const float*)d_in[7];
  const float* Wv   = (const float*)d_in[8];
  const float* bv   = (const float*)d_in[9];
  const float* W0   = (const float*)d_in[10];
  const float* b0   = (const float*)d_in[11];
  const float* Wr   = (const float*)d_in[12];
  const float* br   = (const float*)d_in[13];
  const float* g_ln = (const float*)d_in[14];
  const float* b_ln = (const float*)d_in[15];
  const float* Wms  = (const float*)d_in[16];
  const float* bms  = (const float*)d_in[17];
  const float* Wuas = (const float*)d_in[18];
  float* out = (float*)d_out;

  bf16* ws = (bf16*)d_ws;
  size_t off = 0;
  auto alloc = [&](size_t n) {
    bf16* p = ws + off;
    off += n;
    return p;
  };
  bf16* WqT   = alloc((size_t)NH * NA * ND);       // [h*512][1024] = [1536][1024]
  bf16* WkT   = alloc((size_t)NH * NA * ND);
  bf16* WvT   = alloc((size_t)NH * NA * ND);
  bf16* W0T   = alloc((size_t)NH * NM * NA);       // [h][2048][512]
  bf16* WrT   = alloc((size_t)NH * NRES * NM * NM);// [h*3+j][2048][2048]
  bf16* WmsT  = alloc((size_t)NH * NA * NM);       // [h][512][2048]
  bf16* WuasT = alloc((size_t)ND * NH * NA);       // [1024][1536]
  bf16* Qb    = alloc((size_t)NE * ND);
  bf16* Kb    = alloc((size_t)NE * ND);
  bf16* Qp    = alloc((size_t)NE * NH * NA);       // [E][1536]; later reused as cat
  bf16* Kp    = alloc((size_t)NE * NH * NA);
  bf16* Vp    = alloc((size_t)NE * NH * NA);
  bf16* attn  = alloc((size_t)NH * NE * NA);       // [h][E][512]
  bf16* mbuf  = alloc((size_t)NE * NM);
  bf16* xnb   = alloc((size_t)NE * NM);
  bf16* cat   = Qp;                                // alias: Qp dead after softmax
  if (ws_size < off * sizeof(bf16)) return;  // workspace too small: bail

  const dim3 tb(32, 8);
  transpose_cvt<<<dim3(NA / 32, ND / 32, NH), tb, 0, stream>>>(Wq, WqT, ND, NA);
  transpose_cvt<<<dim3(NA / 32, ND / 32, NH), tb, 0, stream>>>(Wk, WkT, ND, NA);
  transpose_cvt<<<dim3(NA / 32, ND / 32, NH), tb, 0, stream>>>(Wv, WvT, ND, NA);
  transpose_cvt<<<dim3(NM / 32, NA / 32, NH), tb, 0, stream>>>(W0, W0T, NA, NM);
  transpose_cvt<<<dim3(NM / 32, NM / 32, NH * NRES), tb, 0, stream>>>(Wr, WrT,
                                                                      NM, NM);
  transpose_cvt<<<dim3(NA / 32, NM / 32, NH), tb, 0, stream>>>(Wms, WmsT, NM,
                                                               NA);
  transpose_cvt<<<dim3(ND / 32, (NH * NA) / 32, 1), tb, 0, stream>>>(
      Wuas, WuasT, NH * NA, ND);

  gather_kernel<<<NE, 256, 0, stream>>>(h, rep, src, dst, Qb, Kb, out);

  // fused QKV projections: N = H*A = 1536
  launch_gemm<0>(stream, Qb, WqT, bq, Qp, nullptr, NE, NH * NA, ND, NH * NA,
                 0, 0);
  launch_gemm<0>(stream, Kb, WkT, bk, Kp, nullptr, NE, NH * NA, ND, NH * NA,
                 0, 0);
  launch_gemm<0>(stream, Kb, WvT, bv, Vp, nullptr, NE, NH * NA, ND, NH * NA,
                 0, 0);
  softmax_kernel<<<dim3(NE, NH), 256, 0, stream>>>(Qp, Kp, Vp, attn);

  for (int hh = 0; hh < NH; ++hh) {
    const bf16* attn_h = attn + (size_t)hh * NE * NA;
    launch_gemm<0>(stream, attn_h, W0T + (size_t)hh * NM * NA, b0 + hh * NM,
                   mbuf, nullptr, NE, NM, NA, NM, 0, 0);
    for (int j = 0; j < NRES; ++j) {
      const int hj = hh * NRES + j;
      ln_kernel<<<NE, 256, 0, stream>>>(mbuf, xnb, g_ln + (size_t)hj * NM,
                                        b_ln + (size_t)hj * NM);
      launch_gemm<1>(stream, xnb, WrT + (size_t)hj * NM * NM, br + hj * NM,
                     mbuf, mbuf, NE, NM, NM, NM, 0, NM);
    }
    launch_gemm<2>(stream, mbuf, WmsT + (size_t)hh * NA * NM, bms + hh * NA,
                   cat, attn_h, NE, NA, NM, NH * NA, hh * NA, NA);
  }
  launch_gemm<3>(stream, cat, WuasT, nullptr, out, nullptr, NE, ND, NH * NA,
                 ND, 0, 0);
}